// Round 6
// baseline (368.474 us; speedup 1.0000x reference)
//
#include <hip/hip_runtime.h>
#include <math.h>

// Problem constants (match reference)
constexpr int cB = 2, cN = 8192, cS = 4096;
constexpr int cTR = 12;    // stored trans channels (0-5 before, 6-11 after)
constexpr int SCR = 12;    // MLP scratch row stride (8 rows + 4 pad; 16B-aligned)
constexpr int GD = 16;     // grid cells per axis (16^3 = 4096 cells)

typedef unsigned long long ull;

// ---- distance helpers: EXACTLY mirror reference arithmetic ----
// ref: sq = (x*x + y*y) + z*z ; d2 = (sq_i + sq_j) - 2*dot ; d = sqrt(max(d2,1e-12))
__device__ __forceinline__ float d2raw_rn(const float4 a, const float4 b) {
  float dot = __fadd_rn(__fadd_rn(__fmul_rn(a.x, b.x), __fmul_rn(a.y, b.y)), __fmul_rn(a.z, b.z));
  return __fsub_rn(__fadd_rn(a.w, b.w), __fmul_rn(2.0f, dot));
}
__device__ __forceinline__ float dist_rn(const float4 a, const float4 b) {
  return sqrtf(fmaxf(d2raw_rn(a, b), 1e-12f));
}
__device__ __forceinline__ void ce64(ull& a, ull& b) {
  ull lo = a < b ? a : b;
  ull hi = a < b ? b : a;
  a = lo; b = hi;
}

// monotone float<->uint for atomic min/max
__device__ __forceinline__ unsigned fkey(float f) {
  unsigned u = __float_as_uint(f);
  return (u & 0x80000000u) ? ~u : (u | 0x80000000u);
}
__device__ __forceinline__ float funkey(unsigned m) {
  return __uint_as_float((m & 0x80000000u) ? (m ^ 0x80000000u) : ~m);
}

struct GridP { float lox, loy, loz, cwx, cwy, cwz, ivx, ivy, ivz; };
__device__ __forceinline__ GridP load_grid(const unsigned* bbox, int b) {
  GridP g;
  float lx = funkey(bbox[b * 6 + 0]), ly = funkey(bbox[b * 6 + 1]), lz = funkey(bbox[b * 6 + 2]);
  float hx = funkey(bbox[b * 6 + 3]), hy = funkey(bbox[b * 6 + 4]), hz = funkey(bbox[b * 6 + 5]);
  float sx = fmaxf(hx - lx, 1e-9f), sy = fmaxf(hy - ly, 1e-9f), sz = fmaxf(hz - lz, 1e-9f);
  g.lox = lx; g.loy = ly; g.loz = lz;
  g.cwx = sx / GD; g.cwy = sy / GD; g.cwz = sz / GD;
  g.ivx = GD / sx; g.ivy = GD / sy; g.ivz = GD / sz;
  return g;
}
__device__ __forceinline__ int clampi(int v, int lo, int hi) { return v < lo ? lo : (v > hi ? hi : v); }
__device__ __forceinline__ int bin1(float x, float lo, float iv) {
  return clampi((int)floorf((x - lo) * iv), 0, GD - 1);
}

// ---- K0: zero cell counts, init bbox atoms ----
__global__ __launch_bounds__(256) void grid_init_kernel(int* __restrict__ cntBase,  // cntN(8192)+cntS(8192) contiguous
                                                        unsigned* __restrict__ bbox) {
  int t = blockIdx.x * 256 + threadIdx.x;
  if (t < 16384) cntBase[t] = 0;
  if (t < 12) bbox[t] = ((t % 6) < 3) ? 0xFFFFFFFFu : 0u;
}

// ---- K1: pack P[b][n]=(x,y,z,sq); SP[b][s]; emit sampled_xyz; bbox per batch ----
__global__ __launch_bounds__(256) void pack_kernel(const float* __restrict__ xyz,
                                                   const int* __restrict__ smp,
                                                   float4* __restrict__ P,
                                                   float4* __restrict__ SP,
                                                   float* __restrict__ oxyz,
                                                   unsigned* __restrict__ bbox) {
  __shared__ unsigned sbb[6];
  if (threadIdx.x < 3) sbb[threadIdx.x] = 0xFFFFFFFFu;
  else if (threadIdx.x < 6) sbb[threadIdx.x] = 0u;
  __syncthreads();
  int t = blockIdx.x * 256 + threadIdx.x;
  if (t < cB * cN) {
    const float* p = xyz + t * 3;
    float x = p[0], y = p[1], z = p[2];
    float sq = __fadd_rn(__fadd_rn(__fmul_rn(x, x), __fmul_rn(y, y)), __fmul_rn(z, z));
    P[t] = make_float4(x, y, z, sq);
    atomicMin(&sbb[0], fkey(x)); atomicMin(&sbb[1], fkey(y)); atomicMin(&sbb[2], fkey(z));
    atomicMax(&sbb[3], fkey(x)); atomicMax(&sbb[4], fkey(y)); atomicMax(&sbb[5], fkey(z));
  } else if (t < cB * cN + cB * cS) {
    int j = t - cB * cN;
    int b = j >> 12;
    int idx = smp[j];
    const float* p = xyz + (b * cN + idx) * 3;
    float x = p[0], y = p[1], z = p[2];
    float sq = __fadd_rn(__fadd_rn(__fmul_rn(x, x), __fmul_rn(y, y)), __fmul_rn(z, z));
    SP[j] = make_float4(x, y, z, sq);
    oxyz[j * 3 + 0] = x; oxyz[j * 3 + 1] = y; oxyz[j * 3 + 2] = z;
  }
  __syncthreads();
  if (blockIdx.x < 64) {       // P-blocks only; uniform batch per block (32 blocks/batch)
    int b = (blockIdx.x * 256) >> 13;
    if (threadIdx.x < 3) atomicMin(&bbox[b * 6 + threadIdx.x], sbb[threadIdx.x]);
    else if (threadIdx.x < 6) atomicMax(&bbox[b * 6 + threadIdx.x], sbb[threadIdx.x]);
  }
}

// ---- K2: histogram points into cells ----
__global__ __launch_bounds__(256) void grid_count_kernel(const float4* __restrict__ P,
                                                         const float4* __restrict__ SP,
                                                         const unsigned* __restrict__ bbox,
                                                         int* __restrict__ cntN,
                                                         int* __restrict__ cntS) {
  int t = blockIdx.x * 256 + threadIdx.x;
  if (t < cB * cN) {
    int b = t >> 13;
    GridP g = load_grid(bbox, b);
    float4 p = P[t];
    int c = bin1(p.x, g.lox, g.ivx) + GD * (bin1(p.y, g.loy, g.ivy) + GD * bin1(p.z, g.loz, g.ivz));
    atomicAdd(&cntN[b * 4096 + c], 1);
  } else if (t < cB * cN + cB * cS) {
    int j = t - cB * cN;
    int b = j >> 12;
    GridP g = load_grid(bbox, b);
    float4 p = SP[j];
    int c = bin1(p.x, g.lox, g.ivx) + GD * (bin1(p.y, g.loy, g.ivy) + GD * bin1(p.z, g.loz, g.ivz));
    atomicAdd(&cntS[b * 4096 + c], 1);
  }
}

// ---- K3: exclusive prefix sum per (batch, struct); 4 blocks ----
__global__ __launch_bounds__(256) void grid_scan_kernel(const int* __restrict__ cntN,
                                                        const int* __restrict__ cntS,
                                                        int* __restrict__ startsN,
                                                        int* __restrict__ startsS,
                                                        int* __restrict__ curN,
                                                        int* __restrict__ curS) {
  __shared__ int part[256];
  int bid = blockIdx.x;               // 0,1: N-grid b0,b1 ; 2,3: S-grid b0,b1
  const int* cnt = (bid < 2) ? (cntN + bid * 4096) : (cntS + (bid - 2) * 4096);
  int* st  = (bid < 2) ? (startsN + bid * 4097) : (startsS + (bid - 2) * 4097);
  int* cur = (bid < 2) ? (curN + bid * 4096) : (curS + (bid - 2) * 4096);
  int t = threadIdx.x;
  int loc[16], s = 0;
  #pragma unroll
  for (int i = 0; i < 16; i++) { loc[i] = cnt[t * 16 + i]; s += loc[i]; }
  part[t] = s;
  __syncthreads();
  if (t == 0) {
    int acc = 0;
    for (int i = 0; i < 256; i++) { int v = part[i]; part[i] = acc; acc += v; }
  }
  __syncthreads();
  int acc = part[t];
  #pragma unroll
  for (int i = 0; i < 16; i++) { st[t * 16 + i] = acc; cur[t * 16 + i] = acc; acc += loc[i]; }
  if (t == 255) st[4096] = acc;
}

// ---- K4: scatter points into cell-sorted arrays ----
__global__ __launch_bounds__(256) void grid_scatter_kernel(const float4* __restrict__ P,
                                                           const float4* __restrict__ SP,
                                                           const unsigned* __restrict__ bbox,
                                                           int* __restrict__ curN, int* __restrict__ curS,
                                                           float4* __restrict__ sortN, int* __restrict__ idxN,
                                                           float4* __restrict__ sortS, int* __restrict__ idxS) {
  int t = blockIdx.x * 256 + threadIdx.x;
  if (t < cB * cN) {
    int b = t >> 13, n = t & (cN - 1);
    GridP g = load_grid(bbox, b);
    float4 p = P[t];
    int c = bin1(p.x, g.lox, g.ivx) + GD * (bin1(p.y, g.loy, g.ivy) + GD * bin1(p.z, g.loz, g.ivz));
    int pos = atomicAdd(&curN[b * 4096 + c], 1);
    sortN[b * cN + pos] = p; idxN[b * cN + pos] = n;
  } else if (t < cB * cN + cB * cS) {
    int j = t - cB * cN;
    int b = j >> 12, s = j & (cS - 1);
    GridP g = load_grid(bbox, b);
    float4 p = SP[j];
    int c = bin1(p.x, g.lox, g.ivx) + GD * (bin1(p.y, g.loy, g.ivy) + GD * bin1(p.z, g.loz, g.ivz));
    int pos = atomicAdd(&curS[b * 4096 + c], 1);
    sortS[b * cS + pos] = p; idxS[b * cS + pos] = s;
  }
}

__device__ __forceinline__ void scan_cell(int cell, const int* __restrict__ st,
                                          const float4* __restrict__ pts, const int* __restrict__ ids,
                                          float4 q, ull& k0, ull& k1, ull& k2, ull& k3) {
  int s0 = st[cell], s1 = st[cell + 1];
  for (int j = s0; j < s1; ++j) {
    float4 cp = pts[j];
    float f = fmaxf(d2raw_rn(q, cp), 1e-12f);
    ull key = ((ull)__float_as_uint(f) << 32) | (unsigned)ids[j];
    if (key < k3) { k3 = key; ce64(k2, k3); ce64(k1, k2); ce64(k0, k1); }
  }
}

// ---- K5: grid-accelerated exact 4-NN; 1 thread per (query, mode); queries in cell-sorted order ----
// Ring expansion with rigorous termination: stop after ring r when 4 found and the min possible
// TRUE distance^2 to any unscanned cell (minus margin 1e-4 >> d2raw cancellation error ~2e-5)
// exceeds the current 4th-best d2raw. Selection via exact u64 (d2bits, idx) keys == brute force.
__global__ __launch_bounds__(256) void knn_grid_kernel(
    const float4* __restrict__ P, const float4* __restrict__ SP,
    const int* __restrict__ smp, const unsigned* __restrict__ bbox,
    const int* __restrict__ startsN, const int* __restrict__ startsS,
    const float4* __restrict__ sortN, const int* __restrict__ idxN,
    const float4* __restrict__ sortS, const int* __restrict__ idxS,
    float* __restrict__ trans, int* __restrict__ AB, int* __restrict__ AA) {
  int t = blockIdx.x * 256 + threadIdx.x;      // [0, 16384)
  int mode = t >> 13;                          // 0: candidates = all points; 1: sampled
  int slot = t & 8191;
  int b = slot >> 12;
  int j = slot & (cS - 1);
  float4 q = sortS[b * cS + j];                // bit-identical to SP coords
  int s = idxS[b * cS + j];
  int wq = b * cS + s;

  const float4* pts; const int* ids; const int* st;
  if (mode == 0) { pts = sortN + b * cN; ids = idxN + b * cN; st = startsN + b * 4097; }
  else           { pts = sortS + b * cS; ids = idxS + b * cS; st = startsS + b * 4097; }
  GridP g = load_grid(bbox, b);
  int cx = bin1(q.x, g.lox, g.ivx), cy = bin1(q.y, g.loy, g.ivy), cz = bin1(q.z, g.loz, g.ivz);

  const ull K_EMPTY = 0x7F800000FFFFFFFFull;
  ull k0 = K_EMPTY, k1 = K_EMPTY, k2 = K_EMPTY, k3 = K_EMPTY;
  const float INF = __uint_as_float(0x7f800000u);

  for (int r = 0; r < GD; ++r) {
    int x0 = max(0, cx - r), x1 = min(GD - 1, cx + r);
    int y0 = max(0, cy - r), y1 = min(GD - 1, cy + r);
    int z0 = max(0, cz - r), z1 = min(GD - 1, cz + r);
    for (int iz = z0; iz <= z1; ++iz) {
      bool zf = (iz - cz == r) || (cz - iz == r);
      for (int iy = y0; iy <= y1; ++iy) {
        bool face = zf || (iy - cy == r) || (cy - iy == r);
        int rowc = GD * (iy + GD * iz);
        if (face) {
          for (int ix = x0; ix <= x1; ++ix)
            scan_cell(ix + rowc, st, pts, ids, q, k0, k1, k2, k3);
        } else {
          if (cx - r >= 0)     scan_cell(cx - r + rowc, st, pts, ids, q, k0, k1, k2, k3);
          if (cx + r <= GD - 1) scan_cell(cx + r + rowc, st, pts, ids, q, k0, k1, k2, k3);
        }
      }
    }
    if (k3 < K_EMPTY) {
      float tau = __uint_as_float((unsigned)(k3 >> 32));
      float m = INF;
      if (cx - r > 0)      m = fminf(m, q.x - (g.lox + (cx - r) * g.cwx));
      if (cx + r < GD - 1) m = fminf(m, (g.lox + (cx + r + 1) * g.cwx) - q.x);
      if (cy - r > 0)      m = fminf(m, q.y - (g.loy + (cy - r) * g.cwy));
      if (cy + r < GD - 1) m = fminf(m, (g.loy + (cy + r + 1) * g.cwy) - q.y);
      if (cz - r > 0)      m = fminf(m, q.z - (g.loz + (cz - r) * g.cwz));
      if (cz + r < GD - 1) m = fminf(m, (g.loz + (cz + r + 1) * g.cwz) - q.z);
      if (m == INF) break;                               // whole grid scanned
      float mm = m * m * (1.0f - 1e-5f) - 1e-4f;
      if (mm > tau) break;
    }
  }

  // ---- output (identical tail to brute-force version) ----
  int a0 = (int)(unsigned)k0, a1 = (int)(unsigned)k1;
  int a2 = (int)(unsigned)k2, a3 = (int)(unsigned)k3;
  float e1 = sqrtf(__uint_as_float((unsigned)(k1 >> 32)));
  float e2 = sqrtf(__uint_as_float((unsigned)(k2 >> 32)));
  float e3 = sqrtf(__uint_as_float((unsigned)(k3 >> 32)));
  const float4* Cb = mode ? (SP + b * cS) : (P + b * cN);
  float4 p1 = Cb[a1], p2 = Cb[a2], p3 = Cb[a3];
  float* tr = trans + wq * cTR + (mode ? 6 : 0);
  tr[0] = e1; tr[1] = e2; tr[2] = e3;
  tr[3] = dist_rn(p1, p2); tr[4] = dist_rn(p1, p3); tr[5] = dist_rn(p2, p3);
  if (mode == 0) {
    int* ao = AB + wq * 4;
    ao[0] = a0; ao[1] = a1; ao[2] = a2; ao[3] = a3;
  } else {
    const int* sb = smp + b * cS;
    int* ao = AA + wq * 4;
    ao[0] = sb[a0]; ao[1] = sb[a1]; ao[2] = sb[a2]; ao[3] = sb[a3];
  }
}

// 8-row FMA helper: activations via broadcast b128 reads (conflict-free)
__device__ __forceinline__ void fma8(float acc[8], const float* a, float w) {
  float4 x0 = *(const float4*)(a);
  float4 x1 = *(const float4*)(a + 4);
  acc[0] = fmaf(x0.x, w, acc[0]); acc[1] = fmaf(x0.y, w, acc[1]);
  acc[2] = fmaf(x0.z, w, acc[2]); acc[3] = fmaf(x0.w, w, acc[3]);
  acc[4] = fmaf(x1.x, w, acc[4]); acc[5] = fmaf(x1.y, w, acc[5]);
  acc[6] = fmaf(x1.z, w, acc[6]); acc[7] = fmaf(x1.w, w, acc[7]);
}

// ---- K6: fused inter-dists + 3-layer MLP; 4 waves x 8 rows per block, lane = channel ----
__global__ __launch_bounds__(256) void mlp_kernel(
    const float* __restrict__ TR, const float4* __restrict__ P,
    const int* __restrict__ AB, const int* __restrict__ AA,
    const float* __restrict__ feat, const int* __restrict__ smp,
    const float* __restrict__ w1, const float* __restrict__ b1,
    const float* __restrict__ g1, const float* __restrict__ be1,
    const float* __restrict__ w2, const float* __restrict__ b2,
    const float* __restrict__ g2, const float* __restrict__ be2,
    const float* __restrict__ w3, const float* __restrict__ b3,
    const float* __restrict__ g3, const float* __restrict__ be3,
    float* __restrict__ out) {
  __shared__ alignas(16) float sw1[28 * 64];
  __shared__ alignas(16) float sw2[64 * 64];
  __shared__ alignas(16) float sw3[128 * 128];
  __shared__ alignas(16) float scr[4][(28 + 64 + 128) * SCR];

  const int tid = threadIdx.x;
  for (int i = tid; i < 28 * 64 / 4; i += 256) ((float4*)sw1)[i] = ((const float4*)w1)[i];
  for (int i = tid; i < 64 * 64 / 4; i += 256) ((float4*)sw2)[i] = ((const float4*)w2)[i];
  for (int i = tid; i < 128 * 128 / 4; i += 256) ((float4*)sw3)[i] = ((const float4*)w3)[i];

  const int wv = tid >> 6, lane = tid & 63;
  const int grp = blockIdx.x * 4 + wv;          // 0..1023
  const int r0 = grp * 8;                       // rows r0..r0+7 (same batch: 8 | 4096)
  const int b = r0 >> 12;
  const float inv = 1.0f / sqrtf(1.0f + 1e-5f);
  float* tinT  = scr[wv];
  float* act1T = scr[wv] + 28 * SCR;
  float* act2T = scr[wv] + (28 + 64) * SCR;     // ch 0..63 = feat, 64..127 = L2 out

  float pb1 = b1[lane], pg1 = g1[lane] * inv, pe1 = be1[lane];
  float pb2 = b2[lane], pg2 = g2[lane] * inv, pe2 = be2[lane];
  float pb3a = b3[lane],      pg3a = g3[lane] * inv,      pe3a = be3[lane];
  float pb3b = b3[lane + 64], pg3b = g3[lane + 64] * inv, pe3b = be3[lane + 64];

  // stage feat -> act2T ch 0..63 (lane = feature channel)
  {
    const float* fb = feat + (size_t)b * cN * 64;
    #pragma unroll
    for (int r = 0; r < 8; r++) {
      int row = smp[r0 + r];
      act2T[lane * SCR + r] = fb[row * 64 + lane];
    }
  }
  // stage tinT: ch 0..11 from TR, ch 12..27 = inter dists (28ch*8r = 224 items)
  {
    const float4* Pb = P + b * cN;
    #pragma unroll
    for (int t = 0; t < 4; t++) {
      int idx = t * 64 + lane;
      if (idx < 224) {
        int r = idx & 7, ch = idx >> 3;
        float v;
        if (ch < 12) {
          v = TR[(r0 + r) * cTR + ch];
        } else {
          int cc = ch - 12;
          int gi = AB[(r0 + r) * 4 + (cc >> 2)];
          int gj = AA[(r0 + r) * 4 + (cc & 3)];
          v = dist_rn(Pb[gi], Pb[gj]);
        }
        tinT[ch * SCR + r] = v;
      }
    }
  }
  __syncthreads();

  float acc[8];
  // ---- L1: 28 -> 64 ----
  #pragma unroll
  for (int r = 0; r < 8; r++) acc[r] = pb1;
  for (int k = 0; k < 28; k++) fma8(acc, tinT + k * SCR, sw1[k * 64 + lane]);
  #pragma unroll
  for (int r = 0; r < 8; r++) {
    float x = fmaf(acc[r], pg1, pe1);
    act1T[lane * SCR + r] = x >= 0.0f ? x : 0.2f * x;
  }
  __syncthreads();
  // ---- L2: 64 -> 64 ----
  #pragma unroll
  for (int r = 0; r < 8; r++) acc[r] = pb2;
  for (int k = 0; k < 64; k++) fma8(acc, act1T + k * SCR, sw2[k * 64 + lane]);
  #pragma unroll
  for (int r = 0; r < 8; r++) {
    float x = fmaf(acc[r], pg2, pe2);
    act2T[(64 + lane) * SCR + r] = x >= 0.0f ? x : 0.2f * x;
  }
  __syncthreads();
  // ---- L3: 128 -> 128 (lane covers channels lane and lane+64) ----
  float accA[8], accB[8];
  #pragma unroll
  for (int r = 0; r < 8; r++) { accA[r] = pb3a; accB[r] = pb3b; }
  for (int k = 0; k < 128; k++) {
    const float* a = act2T + k * SCR;
    fma8(accA, a, sw3[k * 128 + lane]);
    fma8(accB, a, sw3[k * 128 + 64 + lane]);
  }
  #pragma unroll
  for (int r = 0; r < 8; r++) {
    float xA = fmaf(accA[r], pg3a, pe3a);
    float xB = fmaf(accB[r], pg3b, pe3b);
    xA = xA >= 0.0f ? xA : 0.2f * xA;
    xB = xB >= 0.0f ? xB : 0.2f * xB;
    out[(r0 + r) * 128 + lane] = xA;
    out[(r0 + r) * 128 + 64 + lane] = xB;
  }
}

extern "C" void kernel_launch(void* const* d_in, const int* in_sizes, int n_in,
                              void* d_out, int out_size, void* d_ws, size_t ws_size,
                              hipStream_t stream) {
  const float* xyz  = (const float*)d_in[0];
  const float* feat = (const float*)d_in[1];
  const int*   smp  = (const int*)d_in[2];
  const float* w1   = (const float*)d_in[3];
  const float* b1   = (const float*)d_in[4];
  const float* g1   = (const float*)d_in[5];
  const float* be1  = (const float*)d_in[6];
  const float* w2   = (const float*)d_in[7];
  const float* b2   = (const float*)d_in[8];
  const float* g2   = (const float*)d_in[9];
  const float* be2  = (const float*)d_in[10];
  const float* w3   = (const float*)d_in[11];
  const float* b3   = (const float*)d_in[12];
  const float* g3   = (const float*)d_in[13];
  const float* be3  = (const float*)d_in[14];
  float* out = (float*)d_out;

  char* ws = (char*)d_ws;
  float4*   P       = (float4*)(ws);                 // 262144 B
  float4*   SP      = (float4*)(ws + 262144);        // 131072
  float*    TR      = (float*)(ws + 393216);         // 393216
  int*      AB      = (int*)(ws + 786432);           // 131072
  int*      AA      = (int*)(ws + 917504);           // 131072
  unsigned* bbox    = (unsigned*)(ws + 1048576);     // 48
  int*      cntN    = (int*)(ws + 1048640);          // 32768 (cntS contiguous after)
  int*      cntS    = (int*)(ws + 1081408);          // 32768
  int*      startsN = (int*)(ws + 1114176);          // 32776
  int*      startsS = (int*)(ws + 1146960);          // 32776
  int*      curN    = (int*)(ws + 1179744);          // 32768
  int*      curS    = (int*)(ws + 1212512);          // 32768
  float4*   sortN   = (float4*)(ws + 1245280);       // 262144
  int*      idxN    = (int*)(ws + 1507424);          // 65536
  float4*   sortS   = (float4*)(ws + 1572960);       // 131072
  int*      idxS    = (int*)(ws + 1704032);          // 32768

  grid_init_kernel<<<64, 256, 0, stream>>>(cntN, bbox);
  pack_kernel<<<96, 256, 0, stream>>>(xyz, smp, P, SP, out, bbox);
  grid_count_kernel<<<96, 256, 0, stream>>>(P, SP, bbox, cntN, cntS);
  grid_scan_kernel<<<4, 256, 0, stream>>>(cntN, cntS, startsN, startsS, curN, curS);
  grid_scatter_kernel<<<96, 256, 0, stream>>>(P, SP, bbox, curN, curS, sortN, idxN, sortS, idxS);
  knn_grid_kernel<<<64, 256, 0, stream>>>(P, SP, smp, bbox, startsN, startsS,
                                          sortN, idxN, sortS, idxS, TR, AB, AA);
  mlp_kernel<<<256, 256, 0, stream>>>(TR, P, AB, AA, feat, smp,
                                      w1, b1, g1, be1, w2, b2, g2, be2,
                                      w3, b3, g3, be3, out + cB * cS * 3);
}

// Round 8
// 169.503 us; speedup vs baseline: 2.1738x; 2.1738x over previous
//
#include <hip/hip_runtime.h>
#include <math.h>

// Problem constants (match reference)
constexpr int cB = 2, cN = 8192, cS = 4096;
constexpr int cTR = 12;    // stored trans channels (0-5 before, 6-11 after)
constexpr int CAP = 96;    // survivor buffer slots per (query, mode)

typedef unsigned long long ull;

// ---- distance helpers: EXACTLY mirror reference arithmetic ----
// ref: sq = (x*x + y*y) + z*z ; d2 = (sq_i + sq_j) - 2*dot ; d = sqrt(max(d2,1e-12))
__device__ __forceinline__ float d2q_rn(const float4 q, float cx, float cy, float cz, float cw) {
  float dot = __fadd_rn(__fadd_rn(__fmul_rn(q.x, cx), __fmul_rn(q.y, cy)), __fmul_rn(q.z, cz));
  return __fsub_rn(__fadd_rn(q.w, cw), __fmul_rn(2.0f, dot));
}
// anchor-anchor distance; P entries carry a flag in w's sign bit -> clean with fabs
__device__ __forceinline__ float dist_clean(float4 a, float4 b) {
  float aw = fabsf(a.w), bw = fabsf(b.w);
  float dot = __fadd_rn(__fadd_rn(__fmul_rn(a.x, b.x), __fmul_rn(a.y, b.y)), __fmul_rn(a.z, b.z));
  float d2 = __fsub_rn(__fadd_rn(aw, bw), __fmul_rn(2.0f, dot));
  return sqrtf(fmaxf(d2, 1e-12f));
}
__device__ __forceinline__ void ce64(ull& a, ull& b) {
  ull lo = a < b ? a : b;
  ull hi = a < b ? b : a;
  a = lo; b = hi;
}
// 4th-smallest of per-lane value v across the wave (3 slots padded +inf)
__device__ __forceinline__ float wave_4th(float v) {
  const float INF = __uint_as_float(0x7f800000u);
  float a0 = v, a1 = INF, a2 = INF, a3 = INF;
  #pragma unroll
  for (int off = 1; off < 64; off <<= 1) {
    float s0 = __shfl_xor(a0, off, 64), s1 = __shfl_xor(a1, off, 64);
    float s2 = __shfl_xor(a2, off, 64), s3 = __shfl_xor(a3, off, 64);
    float n0 = fminf(a0, s3), n1 = fminf(a1, s2), n2 = fminf(a2, s1), n3 = fminf(a3, s0);
    float t;
    t = fminf(n0, n2); n2 = fmaxf(n0, n2); n0 = t;
    t = fminf(n1, n3); n3 = fmaxf(n1, n3); n1 = t;
    t = fminf(n0, n1); n1 = fmaxf(n0, n1); n0 = t;
    t = fminf(n2, n3); n3 = fmaxf(n2, n3); n2 = t;
    a0 = n0; a1 = n1; a2 = n2; a3 = n3;
  }
  return a3;
}

// ---- K1: pack P[b][n] = (x,y,z, sq | sampled-flag-signbit); emit sampled_xyz ----
// smp is sorted ascending per batch -> binary-search membership (12 steps, L2-hot).
__global__ __launch_bounds__(256) void pack_kernel(const float* __restrict__ xyz,
                                                   const int* __restrict__ smp,
                                                   float4* __restrict__ P,
                                                   float* __restrict__ oxyz) {
  int t = blockIdx.x * 256 + threadIdx.x;
  if (t < cB * cN) {
    int b = t >> 13, n = t & (cN - 1);
    const float* p = xyz + t * 3;
    float x = p[0], y = p[1], z = p[2];
    float sq = __fadd_rn(__fadd_rn(__fmul_rn(x, x), __fmul_rn(y, y)), __fmul_rn(z, z));
    const int* sb = smp + b * cS;
    int lo = 0, hi = cS;
    while (lo < hi) { int mid = (lo + hi) >> 1; if (sb[mid] < n) lo = mid + 1; else hi = mid; }
    bool flg = (lo < cS) && (sb[lo] == n);
    float w = flg ? __uint_as_float(__float_as_uint(sq) | 0x80000000u) : sq;
    P[t] = make_float4(x, y, z, w);
  } else if (t < cB * cN + cB * cS) {
    int j = t - cB * cN;
    int b = j >> 12;
    int idx = smp[j];
    const float* p = xyz + (b * cN + idx) * 3;
    oxyz[j * 3 + 0] = p[0]; oxyz[j * 3 + 1] = p[1]; oxyz[j * 3 + 2] = p[2];
  }
}

// ---- K2: fused two-pass 4-NN, both modes in ONE scan of P ----
// 1024 blocks x 256 thr (4 waves). Block owns 8 queries; waves (0,1)->queries 0-3,
// (2,3)->queries 4-7; wave parity scans half of each 1024-candidate tile.
// Pass A: per-lane raw-d2 minima (all-candidates + flagged-only). tau = fmax(4th-smallest
// lane-min, 1e-12) per wave (valid upper bound on d(4): the 4 smallest lane-minima are 4
// distinct real distances, so their max >= d(4)). Pass B: re-scan, push survivors
// (fc <= tau) into per-(query,mode) LDS buffers; exact u64 (d2bits, P-idx) butterfly.
// Mode-1 tie-break by P-index == by SP-index because smp is sorted (monotone map);
// AA output = smp[SP-idx] = P-idx directly.
__global__ __launch_bounds__(256) void knn_kernel(const float4* __restrict__ P,
                                                  const int* __restrict__ smp,
                                                  float* __restrict__ trans,
                                                  int* __restrict__ AB,
                                                  int* __restrict__ AA) {
  __shared__ alignas(16) float4 sC[1024];
  __shared__ ull sBuf[16][CAP];
  __shared__ int sCnt[16];

  const int wv = threadIdx.x >> 6, lane = threadIdx.x & 63;
  const int par = wv & 1;                 // candidate half
  const int grpq = (wv >> 1) * 4;         // first local query of this wave-pair
  const int qbase = blockIdx.x * 8;       // 8 | 4096 -> same batch
  const int b = qbase >> 12;
  const float4* Pb = P + b * cN;
  const float INF = __uint_as_float(0x7f800000u);

  float4 pq[4];
  #pragma unroll
  for (int qi = 0; qi < 4; qi++) {
    float4 q = Pb[smp[qbase + grpq + qi]];
    q.w = fabsf(q.w);                     // queries are sampled -> flagged; clean
    pq[qi] = q;
  }

  float mnA[4] = {INF, INF, INF, INF};    // all-candidate minima (raw d2)
  float mnS[4] = {INF, INF, INF, INF};    // sampled-candidate minima

  // ---- Pass A ----
  for (int t0 = 0; t0 < cN; t0 += 1024) {
    for (int j = threadIdx.x; j < 1024; j += 256) sC[j] = Pb[t0 + j];
    __syncthreads();
    const int base = par * 512;
    #pragma unroll 4
    for (int u = 0; u < 8; u++) {
      float4 cp = sC[base + u * 64 + lane];
      int wb = __float_as_int(cp.w);
      float cw = __int_as_float(wb & 0x7fffffff);
      bool flg = wb < 0;
      #pragma unroll
      for (int qi = 0; qi < 4; qi++) {
        float f = d2q_rn(pq[qi], cp.x, cp.y, cp.z, cw);
        mnA[qi] = fminf(mnA[qi], f);
        mnS[qi] = fminf(mnS[qi], flg ? f : INF);
      }
    }
    __syncthreads();
  }

  float tauA[4], tauS[4];
  #pragma unroll
  for (int qi = 0; qi < 4; qi++) {
    tauA[qi] = fmaxf(wave_4th(mnA[qi]), 1e-12f);
    tauS[qi] = fmaxf(wave_4th(mnS[qi]), 1e-12f);
  }
  if (threadIdx.x < 16) sCnt[threadIdx.x] = 0;

  // ---- Pass B ----
  for (int t0 = 0; t0 < cN; t0 += 1024) {
    for (int j = threadIdx.x; j < 1024; j += 256) sC[j] = Pb[t0 + j];
    __syncthreads();                       // also publishes sCnt=0 on first tile
    const int base = par * 512;
    #pragma unroll 2
    for (int u = 0; u < 8; u++) {
      float4 cp = sC[base + u * 64 + lane];
      int wb = __float_as_int(cp.w);
      float cw = __int_as_float(wb & 0x7fffffff);
      bool flg = wb < 0;
      int m = t0 + base + u * 64 + lane;
      #pragma unroll
      for (int qi = 0; qi < 4; qi++) {
        float f = d2q_rn(pq[qi], cp.x, cp.y, cp.z, cw);
        float fc = fmaxf(f, 1e-12f);
        ull key = ((ull)__float_as_uint(fc) << 32) | (unsigned)m;
        int bi = (grpq + qi) * 2;
        if (fc <= tauA[qi]) {              // rare
          int slot = atomicAdd(&sCnt[bi], 1);
          if (slot < CAP) sBuf[bi][slot] = key;
        }
        if (flg && fc <= tauS[qi]) {       // rare
          int slot = atomicAdd(&sCnt[bi + 1], 1);
          if (slot < CAP) sBuf[bi + 1][slot] = key;
        }
      }
    }
    __syncthreads();
  }

  // ---- final exact top-4 per (query, mode): u64 butterfly over survivors ----
  const ull KE = 0x7F800000FFFFFFFFull;
  for (int j = 0; j < 4; j++) {
    int pidx = wv * 4 + j;                // 16 pairs / 4 waves
    int qloc = pidx >> 1, mode = pidx & 1;
    int cnt = sCnt[pidx]; cnt = cnt > CAP ? CAP : cnt;
    ull k0 = (lane < cnt) ? sBuf[pidx][lane] : KE;
    ull k1 = (lane + 64 < cnt) ? sBuf[pidx][lane + 64] : KE;
    if (k1 < k0) { ull t = k0; k0 = k1; k1 = t; }
    ull k2 = KE, k3 = KE;
    #pragma unroll
    for (int off = 1; off < 64; off <<= 1) {
      ull b0 = __shfl_xor(k0, off, 64), b1 = __shfl_xor(k1, off, 64);
      ull b2 = __shfl_xor(k2, off, 64), b3 = __shfl_xor(k3, off, 64);
      ull m0 = k0 < b3 ? k0 : b3;
      ull m1 = k1 < b2 ? k1 : b2;
      ull m2 = k2 < b1 ? k2 : b1;
      ull m3 = k3 < b0 ? k3 : b0;
      ce64(m0, m2); ce64(m1, m3); ce64(m0, m1); ce64(m2, m3);
      k0 = m0; k1 = m1; k2 = m2; k3 = m3;
    }
    if (lane == 0) {
      int wq = qbase + qloc;
      int a0 = (int)(unsigned)k0, a1 = (int)(unsigned)k1;
      int a2 = (int)(unsigned)k2, a3 = (int)(unsigned)k3;
      float e1 = sqrtf(__uint_as_float((unsigned)(k1 >> 32)));
      float e2 = sqrtf(__uint_as_float((unsigned)(k2 >> 32)));
      float e3 = sqrtf(__uint_as_float((unsigned)(k3 >> 32)));
      float4 p1 = Pb[a1], p2 = Pb[a2], p3 = Pb[a3];
      float* tr = trans + wq * cTR + (mode ? 6 : 0);
      tr[0] = e1; tr[1] = e2; tr[2] = e3;
      tr[3] = dist_clean(p1, p2); tr[4] = dist_clean(p1, p3); tr[5] = dist_clean(p2, p3);
      int* ao = (mode ? AA : AB) + wq * 4;
      ao[0] = a0; ao[1] = a1; ao[2] = a2; ao[3] = a3;   // P-space ids for both modes
    }
  }
}

// ---- K3: fused inter-dists + 3-layer MLP ----
// 2048 single-wave blocks, 4 rows/wave, lane = channel. Acts transposed in 3.5 KB LDS
// (broadcast b128 reads); weights streamed from global (L2-hot coalesced) - no LDS staging.
__global__ __launch_bounds__(64) void mlp_kernel(
    const float* __restrict__ TR, const float4* __restrict__ P,
    const int* __restrict__ AB, const int* __restrict__ AA,
    const float* __restrict__ feat, const int* __restrict__ smp,
    const float* __restrict__ w1, const float* __restrict__ b1,
    const float* __restrict__ g1, const float* __restrict__ be1,
    const float* __restrict__ w2, const float* __restrict__ b2,
    const float* __restrict__ g2, const float* __restrict__ be2,
    const float* __restrict__ w3, const float* __restrict__ b3,
    const float* __restrict__ g3, const float* __restrict__ be3,
    float* __restrict__ out) {
  __shared__ alignas(16) float tinT[28 * 4];
  __shared__ alignas(16) float act1T[64 * 4];
  __shared__ alignas(16) float act2T[128 * 4];   // ch 0..63 = feat, 64..127 = L2 out

  const int lane = threadIdx.x;
  const int r0 = blockIdx.x * 4;                 // rows r0..r0+3 (same batch: 4 | 4096)
  const int b = r0 >> 12;
  const float inv = 1.0f / sqrtf(1.0f + 1e-5f);

  float pb1 = b1[lane], pg1 = g1[lane] * inv, pe1 = be1[lane];
  float pb2 = b2[lane], pg2 = g2[lane] * inv, pe2 = be2[lane];
  float pb3a = b3[lane],      pg3a = g3[lane] * inv,      pe3a = be3[lane];
  float pb3b = b3[lane + 64], pg3b = g3[lane + 64] * inv, pe3b = be3[lane + 64];

  // stage feat -> act2T ch 0..63
  {
    const float* fb = feat + (size_t)b * cN * 64;
    float4 v;
    v.x = fb[smp[r0 + 0] * 64 + lane];
    v.y = fb[smp[r0 + 1] * 64 + lane];
    v.z = fb[smp[r0 + 2] * 64 + lane];
    v.w = fb[smp[r0 + 3] * 64 + lane];
    *(float4*)&act2T[lane * 4] = v;
  }
  // stage tinT: ch 0..11 from TR, ch 12..27 = inter dists (28ch*4r = 112 items)
  {
    const float4* Pb = P + b * cN;
    #pragma unroll
    for (int t = 0; t < 2; t++) {
      int idx = t * 64 + lane;
      if (idx < 112) {
        int r = idx & 3, ch = idx >> 2;
        float v;
        if (ch < 12) {
          v = TR[(r0 + r) * cTR + ch];
        } else {
          int cc = ch - 12;
          int gi = AB[(r0 + r) * 4 + (cc >> 2)];
          int gj = AA[(r0 + r) * 4 + (cc & 3)];
          v = dist_clean(Pb[gi], Pb[gj]);
        }
        tinT[ch * 4 + r] = v;
      }
    }
  }
  __syncthreads();

  // ---- L1: 28 -> 64 ----
  {
    float4 acc = make_float4(pb1, pb1, pb1, pb1);
    for (int k = 0; k < 28; k++) {
      float w = w1[k * 64 + lane];
      float4 a = *(const float4*)&tinT[k * 4];
      acc.x = fmaf(a.x, w, acc.x); acc.y = fmaf(a.y, w, acc.y);
      acc.z = fmaf(a.z, w, acc.z); acc.w = fmaf(a.w, w, acc.w);
    }
    float4 o;
    o.x = fmaf(acc.x, pg1, pe1); o.y = fmaf(acc.y, pg1, pe1);
    o.z = fmaf(acc.z, pg1, pe1); o.w = fmaf(acc.w, pg1, pe1);
    o.x = o.x >= 0.0f ? o.x : 0.2f * o.x; o.y = o.y >= 0.0f ? o.y : 0.2f * o.y;
    o.z = o.z >= 0.0f ? o.z : 0.2f * o.z; o.w = o.w >= 0.0f ? o.w : 0.2f * o.w;
    __syncthreads();
    *(float4*)&act1T[lane * 4] = o;
  }
  __syncthreads();
  // ---- L2: 64 -> 64 ----
  {
    float4 acc = make_float4(pb2, pb2, pb2, pb2);
    for (int k = 0; k < 64; k++) {
      float w = w2[k * 64 + lane];
      float4 a = *(const float4*)&act1T[k * 4];
      acc.x = fmaf(a.x, w, acc.x); acc.y = fmaf(a.y, w, acc.y);
      acc.z = fmaf(a.z, w, acc.z); acc.w = fmaf(a.w, w, acc.w);
    }
    float4 o;
    o.x = fmaf(acc.x, pg2, pe2); o.y = fmaf(acc.y, pg2, pe2);
    o.z = fmaf(acc.z, pg2, pe2); o.w = fmaf(acc.w, pg2, pe2);
    o.x = o.x >= 0.0f ? o.x : 0.2f * o.x; o.y = o.y >= 0.0f ? o.y : 0.2f * o.y;
    o.z = o.z >= 0.0f ? o.z : 0.2f * o.z; o.w = o.w >= 0.0f ? o.w : 0.2f * o.w;
    *(float4*)&act2T[(64 + lane) * 4] = o;
  }
  __syncthreads();
  // ---- L3: 128 -> 128 (lane covers channels lane and lane+64) ----
  {
    float4 aA = make_float4(pb3a, pb3a, pb3a, pb3a);
    float4 aB = make_float4(pb3b, pb3b, pb3b, pb3b);
    for (int k = 0; k < 128; k++) {
      float wA = w3[k * 128 + lane];
      float wB = w3[k * 128 + 64 + lane];
      float4 a = *(const float4*)&act2T[k * 4];
      aA.x = fmaf(a.x, wA, aA.x); aA.y = fmaf(a.y, wA, aA.y);
      aA.z = fmaf(a.z, wA, aA.z); aA.w = fmaf(a.w, wA, aA.w);
      aB.x = fmaf(a.x, wB, aB.x); aB.y = fmaf(a.y, wB, aB.y);
      aB.z = fmaf(a.z, wB, aB.z); aB.w = fmaf(a.w, wB, aB.w);
    }
    float rA[4] = {aA.x, aA.y, aA.z, aA.w};
    float rB[4] = {aB.x, aB.y, aB.z, aB.w};
    #pragma unroll
    for (int r = 0; r < 4; r++) {
      float xA = fmaf(rA[r], pg3a, pe3a);
      float xB = fmaf(rB[r], pg3b, pe3b);
      xA = xA >= 0.0f ? xA : 0.2f * xA;
      xB = xB >= 0.0f ? xB : 0.2f * xB;
      out[(r0 + r) * 128 + lane] = xA;
      out[(r0 + r) * 128 + 64 + lane] = xB;
    }
  }
}

extern "C" void kernel_launch(void* const* d_in, const int* in_sizes, int n_in,
                              void* d_out, int out_size, void* d_ws, size_t ws_size,
                              hipStream_t stream) {
  const float* xyz  = (const float*)d_in[0];
  const float* feat = (const float*)d_in[1];
  const int*   smp  = (const int*)d_in[2];
  const float* w1   = (const float*)d_in[3];
  const float* b1   = (const float*)d_in[4];
  const float* g1   = (const float*)d_in[5];
  const float* be1  = (const float*)d_in[6];
  const float* w2   = (const float*)d_in[7];
  const float* b2   = (const float*)d_in[8];
  const float* g2   = (const float*)d_in[9];
  const float* be2  = (const float*)d_in[10];
  const float* w3   = (const float*)d_in[11];
  const float* b3   = (const float*)d_in[12];
  const float* g3   = (const float*)d_in[13];
  const float* be3  = (const float*)d_in[14];
  float* out = (float*)d_out;

  char* ws = (char*)d_ws;
  float4* P  = (float4*)(ws);                     // B*N*16   = 262144 B
  float*  TR = (float*)(ws + 262144);             // B*S*12*4 = 393216 B
  int*    AB = (int*)(ws + 655360);               // B*S*4*4  = 131072 B
  int*    AA = (int*)(ws + 786432);               // B*S*4*4  = 131072 B

  pack_kernel<<<96, 256, 0, stream>>>(xyz, smp, P, out);
  knn_kernel<<<1024, 256, 0, stream>>>(P, smp, TR, AB, AA);
  mlp_kernel<<<2048, 64, 0, stream>>>(TR, P, AB, AA, feat, smp,
                                      w1, b1, g1, be1, w2, b2, g2, be2,
                                      w3, b3, g3, be3, out + cB * cS * 3);
}

// Round 9
// 155.165 us; speedup vs baseline: 2.3747x; 1.0924x over previous
//
#include <hip/hip_runtime.h>
#include <math.h>

// Problem constants (match reference)
constexpr int cB = 2, cN = 8192, cS = 4096;
constexpr int cTR = 12;    // stored trans channels (0-5 before, 6-11 after)
constexpr int CAP = 96;    // survivor buffer slots per (query, mode)
constexpr int TILE = 512;  // candidate tile (double-buffered)
constexpr int NT = cN / TILE;

typedef unsigned long long ull;

// ---- exact distance: EXACTLY mirrors reference arithmetic ----
// ref: sq = (x*x + y*y) + z*z ; d2 = (sq_i + sq_j) - 2*dot ; d = sqrt(max(d2,1e-12))
__device__ __forceinline__ float d2q_rn(const float4 q, float cx, float cy, float cz, float cw) {
  float dot = __fadd_rn(__fadd_rn(__fmul_rn(q.x, cx), __fmul_rn(q.y, cy)), __fmul_rn(q.z, cz));
  return __fsub_rn(__fadd_rn(q.w, cw), __fmul_rn(2.0f, dot));
}
// anchor-anchor distance; P entries carry a flag in w's sign bit -> clean with fabs
__device__ __forceinline__ float dist_clean(float4 a, float4 b) {
  float aw = fabsf(a.w), bw = fabsf(b.w);
  float dot = __fadd_rn(__fadd_rn(__fmul_rn(a.x, b.x), __fmul_rn(a.y, b.y)), __fmul_rn(a.z, b.z));
  float d2 = __fsub_rn(__fadd_rn(aw, bw), __fmul_rn(2.0f, dot));
  return sqrtf(fmaxf(d2, 1e-12f));
}
__device__ __forceinline__ void ce64(ull& a, ull& b) {
  ull lo = a < b ? a : b;
  ull hi = a < b ? b : a;
  a = lo; b = hi;
}
// 4th-smallest of per-lane value v across the wave (3 slots padded +inf)
__device__ __forceinline__ float wave_4th(float v) {
  const float INF = __uint_as_float(0x7f800000u);
  float a0 = v, a1 = INF, a2 = INF, a3 = INF;
  #pragma unroll
  for (int off = 1; off < 64; off <<= 1) {
    float s0 = __shfl_xor(a0, off, 64), s1 = __shfl_xor(a1, off, 64);
    float s2 = __shfl_xor(a2, off, 64), s3 = __shfl_xor(a3, off, 64);
    float n0 = fminf(a0, s3), n1 = fminf(a1, s2), n2 = fminf(a2, s1), n3 = fminf(a3, s0);
    float t;
    t = fminf(n0, n2); n2 = fmaxf(n0, n2); n0 = t;
    t = fminf(n1, n3); n3 = fmaxf(n1, n3); n1 = t;
    t = fminf(n0, n1); n1 = fmaxf(n0, n1); n0 = t;
    t = fminf(n2, n3); n3 = fmaxf(n2, n3); n2 = t;
    a0 = n0; a1 = n1; a2 = n2; a3 = n3;
  }
  return a3;
}

// ---- K1: pack P[b][n] = (x,y,z, sq | sampled-flag-signbit); emit sampled_xyz ----
__global__ __launch_bounds__(256) void pack_kernel(const float* __restrict__ xyz,
                                                   const int* __restrict__ smp,
                                                   float4* __restrict__ P,
                                                   float* __restrict__ oxyz) {
  int t = blockIdx.x * 256 + threadIdx.x;
  if (t < cB * cN) {
    int b = t >> 13, n = t & (cN - 1);
    const float* p = xyz + t * 3;
    float x = p[0], y = p[1], z = p[2];
    float sq = __fadd_rn(__fadd_rn(__fmul_rn(x, x), __fmul_rn(y, y)), __fmul_rn(z, z));
    const int* sb = smp + b * cS;
    int lo = 0, hi = cS;
    while (lo < hi) { int mid = (lo + hi) >> 1; if (sb[mid] < n) lo = mid + 1; else hi = mid; }
    bool flg = (lo < cS) && (sb[lo] == n);
    float w = flg ? __uint_as_float(__float_as_uint(sq) | 0x80000000u) : sq;
    P[t] = make_float4(x, y, z, w);
  } else if (t < cB * cN + cB * cS) {
    int j = t - cB * cN;
    int b = j >> 12;
    int idx = smp[j];
    const float* p = xyz + (b * cN + idx) * 3;
    oxyz[j * 3 + 0] = p[0]; oxyz[j * 3 + 1] = p[1]; oxyz[j * 3 + 2] = p[2];
  }
}

// ---- K2: fused two-pass 4-NN, fast-FMA gating + exact survivor re-rank ----
// 1024 blocks x 4 waves; block owns 8 queries; wave-pair parity splits each tile.
// Pass A: per-lane minima of FAST f (1 add + 3 fma). tau_fast = wave 4th-smallest lane-min
// (>= 4 candidates have fast-f <= tau_fast). Gate = tau_fast + MARGIN where MARGIN (2e-3)
// >> 2*max|f_fast - f_exact| (~8e-5) -> every EXACT top-4 candidate passes the gate.
// Pass B: fast-gated survivors recompute exact reference-rounded d2 and push exact u64
// (d2bits, P-idx) keys; butterfly select == brute-force selection bit-identically.
// LDS double-buffered: one barrier/tile, next tile's global loads overlap compute.
__global__ __launch_bounds__(256) void knn_kernel(const float4* __restrict__ P,
                                                  const int* __restrict__ smp,
                                                  float* __restrict__ trans,
                                                  int* __restrict__ AB,
                                                  int* __restrict__ AA) {
  __shared__ alignas(16) float4 sC[2][TILE];
  __shared__ ull sBuf[16][CAP];
  __shared__ int sCnt[16];

  const int tid = threadIdx.x;
  const int wv = tid >> 6, lane = tid & 63;
  const int par = wv & 1;                 // candidate half within tile
  const int grpq = (wv >> 1) * 4;         // first local query of this wave-pair
  const int qbase = blockIdx.x * 8;       // 8 | 4096 -> same batch
  const int b = qbase >> 12;
  const float4* Pb = P + b * cN;
  const float INF = __uint_as_float(0x7f800000u);
  const float MARGIN = 2e-3f;

  float4 pq[4];   // exact coords (w cleaned)
  float4 qf[4];   // fast coeffs: (-2x, -2y, -2z, |w|)
  #pragma unroll
  for (int qi = 0; qi < 4; qi++) {
    float4 q = Pb[smp[qbase + grpq + qi]];
    q.w = fabsf(q.w);
    pq[qi] = q;
    qf[qi] = make_float4(-2.0f * q.x, -2.0f * q.y, -2.0f * q.z, q.w);
  }
  if (tid < 16) sCnt[tid] = 0;

  float mnA[4] = {INF, INF, INF, INF};
  float mnS[4] = {INF, INF, INF, INF};

  // ---- Pass A (pipelined) ----
  {
    float4 ra = Pb[tid], rb = Pb[256 + tid];
    sC[0][tid] = ra; sC[0][256 + tid] = rb;
    __syncthreads();
    for (int t = 0; t < NT; ++t) {
      int nt = t + 1;
      if (nt < NT) { ra = Pb[nt * TILE + tid]; rb = Pb[nt * TILE + 256 + tid]; }
      const float4* cs = sC[t & 1] + par * 256;
      #pragma unroll 4
      for (int u = 0; u < 4; ++u) {
        float4 cp = cs[u * 64 + lane];
        int wb = __float_as_int(cp.w);
        float cw = __int_as_float(wb & 0x7fffffff);
        bool flg = wb < 0;
        #pragma unroll
        for (int qi = 0; qi < 4; ++qi) {
          float f = fmaf(qf[qi].z, cp.z,
                    fmaf(qf[qi].y, cp.y,
                    fmaf(qf[qi].x, cp.x, cw + qf[qi].w)));
          mnA[qi] = fminf(mnA[qi], f);
          mnS[qi] = fminf(mnS[qi], flg ? f : INF);
        }
      }
      if (nt < NT) { sC[nt & 1][tid] = ra; sC[nt & 1][256 + tid] = rb; }
      __syncthreads();
    }
  }

  float gA[4], gS[4];
  #pragma unroll
  for (int qi = 0; qi < 4; qi++) {
    gA[qi] = wave_4th(mnA[qi]) + MARGIN;
    gS[qi] = wave_4th(mnS[qi]) + MARGIN;
  }

  // ---- Pass B (pipelined, fast gate -> exact key) ----
  {
    float4 ra = Pb[tid], rb = Pb[256 + tid];
    sC[0][tid] = ra; sC[0][256 + tid] = rb;
    __syncthreads();
    for (int t = 0; t < NT; ++t) {
      int nt = t + 1;
      if (nt < NT) { ra = Pb[nt * TILE + tid]; rb = Pb[nt * TILE + 256 + tid]; }
      const int mbase = t * TILE + par * 256;
      const float4* cs = sC[t & 1] + par * 256;
      #pragma unroll 2
      for (int u = 0; u < 4; ++u) {
        float4 cp = cs[u * 64 + lane];
        int wb = __float_as_int(cp.w);
        float cw = __int_as_float(wb & 0x7fffffff);
        bool flg = wb < 0;
        int m = mbase + u * 64 + lane;
        #pragma unroll
        for (int qi = 0; qi < 4; ++qi) {
          float f = fmaf(qf[qi].z, cp.z,
                    fmaf(qf[qi].y, cp.y,
                    fmaf(qf[qi].x, cp.x, cw + qf[qi].w)));
          if (f <= gA[qi]) {             // rare
            float fe = fmaxf(d2q_rn(pq[qi], cp.x, cp.y, cp.z, cw), 1e-12f);
            ull key = ((ull)__float_as_uint(fe) << 32) | (unsigned)m;
            int bi = (grpq + qi) * 2;
            int slot = atomicAdd(&sCnt[bi], 1);
            if (slot < CAP) sBuf[bi][slot] = key;
          }
          if (flg && f <= gS[qi]) {      // rare
            float fe = fmaxf(d2q_rn(pq[qi], cp.x, cp.y, cp.z, cw), 1e-12f);
            ull key = ((ull)__float_as_uint(fe) << 32) | (unsigned)m;
            int bi = (grpq + qi) * 2 + 1;
            int slot = atomicAdd(&sCnt[bi], 1);
            if (slot < CAP) sBuf[bi][slot] = key;
          }
        }
      }
      if (nt < NT) { sC[nt & 1][tid] = ra; sC[nt & 1][256 + tid] = rb; }
      __syncthreads();
    }
  }

  // ---- final exact top-4 per (query, mode): u64 butterfly over survivors ----
  const ull KE = 0x7F800000FFFFFFFFull;
  for (int j = 0; j < 4; j++) {
    int pidx = wv * 4 + j;                // 16 pairs / 4 waves
    int qloc = pidx >> 1, mode = pidx & 1;
    int cnt = sCnt[pidx]; cnt = cnt > CAP ? CAP : cnt;
    ull k0 = (lane < cnt) ? sBuf[pidx][lane] : KE;
    ull k1 = (lane + 64 < cnt) ? sBuf[pidx][lane + 64] : KE;
    if (k1 < k0) { ull t = k0; k0 = k1; k1 = t; }
    ull k2 = KE, k3 = KE;
    #pragma unroll
    for (int off = 1; off < 64; off <<= 1) {
      ull b0 = __shfl_xor(k0, off, 64), b1 = __shfl_xor(k1, off, 64);
      ull b2 = __shfl_xor(k2, off, 64), b3 = __shfl_xor(k3, off, 64);
      ull m0 = k0 < b3 ? k0 : b3;
      ull m1 = k1 < b2 ? k1 : b2;
      ull m2 = k2 < b1 ? k2 : b1;
      ull m3 = k3 < b0 ? k3 : b0;
      ce64(m0, m2); ce64(m1, m3); ce64(m0, m1); ce64(m2, m3);
      k0 = m0; k1 = m1; k2 = m2; k3 = m3;
    }
    if (lane == 0) {
      int wq = qbase + qloc;
      int a0 = (int)(unsigned)k0, a1 = (int)(unsigned)k1;
      int a2 = (int)(unsigned)k2, a3 = (int)(unsigned)k3;
      float e1 = sqrtf(__uint_as_float((unsigned)(k1 >> 32)));
      float e2 = sqrtf(__uint_as_float((unsigned)(k2 >> 32)));
      float e3 = sqrtf(__uint_as_float((unsigned)(k3 >> 32)));
      float4 p1 = Pb[a1], p2 = Pb[a2], p3 = Pb[a3];
      float* tr = trans + wq * cTR + (mode ? 6 : 0);
      tr[0] = e1; tr[1] = e2; tr[2] = e3;
      tr[3] = dist_clean(p1, p2); tr[4] = dist_clean(p1, p3); tr[5] = dist_clean(p2, p3);
      int* ao = (mode ? AA : AB) + wq * 4;
      ao[0] = a0; ao[1] = a1; ao[2] = a2; ao[3] = a3;   // P-space ids for both modes
    }
  }
}

// ---- K3: fused inter-dists + 3-layer MLP (unchanged from round 8) ----
__global__ __launch_bounds__(64) void mlp_kernel(
    const float* __restrict__ TR, const float4* __restrict__ P,
    const int* __restrict__ AB, const int* __restrict__ AA,
    const float* __restrict__ feat, const int* __restrict__ smp,
    const float* __restrict__ w1, const float* __restrict__ b1,
    const float* __restrict__ g1, const float* __restrict__ be1,
    const float* __restrict__ w2, const float* __restrict__ b2,
    const float* __restrict__ g2, const float* __restrict__ be2,
    const float* __restrict__ w3, const float* __restrict__ b3,
    const float* __restrict__ g3, const float* __restrict__ be3,
    float* __restrict__ out) {
  __shared__ alignas(16) float tinT[28 * 4];
  __shared__ alignas(16) float act1T[64 * 4];
  __shared__ alignas(16) float act2T[128 * 4];   // ch 0..63 = feat, 64..127 = L2 out

  const int lane = threadIdx.x;
  const int r0 = blockIdx.x * 4;
  const int b = r0 >> 12;
  const float inv = 1.0f / sqrtf(1.0f + 1e-5f);

  float pb1 = b1[lane], pg1 = g1[lane] * inv, pe1 = be1[lane];
  float pb2 = b2[lane], pg2 = g2[lane] * inv, pe2 = be2[lane];
  float pb3a = b3[lane],      pg3a = g3[lane] * inv,      pe3a = be3[lane];
  float pb3b = b3[lane + 64], pg3b = g3[lane + 64] * inv, pe3b = be3[lane + 64];

  {
    const float* fb = feat + (size_t)b * cN * 64;
    float4 v;
    v.x = fb[smp[r0 + 0] * 64 + lane];
    v.y = fb[smp[r0 + 1] * 64 + lane];
    v.z = fb[smp[r0 + 2] * 64 + lane];
    v.w = fb[smp[r0 + 3] * 64 + lane];
    *(float4*)&act2T[lane * 4] = v;
  }
  {
    const float4* Pb = P + b * cN;
    #pragma unroll
    for (int t = 0; t < 2; t++) {
      int idx = t * 64 + lane;
      if (idx < 112) {
        int r = idx & 3, ch = idx >> 2;
        float v;
        if (ch < 12) {
          v = TR[(r0 + r) * cTR + ch];
        } else {
          int cc = ch - 12;
          int gi = AB[(r0 + r) * 4 + (cc >> 2)];
          int gj = AA[(r0 + r) * 4 + (cc & 3)];
          v = dist_clean(Pb[gi], Pb[gj]);
        }
        tinT[ch * 4 + r] = v;
      }
    }
  }
  __syncthreads();

  {
    float4 acc = make_float4(pb1, pb1, pb1, pb1);
    for (int k = 0; k < 28; k++) {
      float w = w1[k * 64 + lane];
      float4 a = *(const float4*)&tinT[k * 4];
      acc.x = fmaf(a.x, w, acc.x); acc.y = fmaf(a.y, w, acc.y);
      acc.z = fmaf(a.z, w, acc.z); acc.w = fmaf(a.w, w, acc.w);
    }
    float4 o;
    o.x = fmaf(acc.x, pg1, pe1); o.y = fmaf(acc.y, pg1, pe1);
    o.z = fmaf(acc.z, pg1, pe1); o.w = fmaf(acc.w, pg1, pe1);
    o.x = o.x >= 0.0f ? o.x : 0.2f * o.x; o.y = o.y >= 0.0f ? o.y : 0.2f * o.y;
    o.z = o.z >= 0.0f ? o.z : 0.2f * o.z; o.w = o.w >= 0.0f ? o.w : 0.2f * o.w;
    __syncthreads();
    *(float4*)&act1T[lane * 4] = o;
  }
  __syncthreads();
  {
    float4 acc = make_float4(pb2, pb2, pb2, pb2);
    for (int k = 0; k < 64; k++) {
      float w = w2[k * 64 + lane];
      float4 a = *(const float4*)&act1T[k * 4];
      acc.x = fmaf(a.x, w, acc.x); acc.y = fmaf(a.y, w, acc.y);
      acc.z = fmaf(a.z, w, acc.z); acc.w = fmaf(a.w, w, acc.w);
    }
    float4 o;
    o.x = fmaf(acc.x, pg2, pe2); o.y = fmaf(acc.y, pg2, pe2);
    o.z = fmaf(acc.z, pg2, pe2); o.w = fmaf(acc.w, pg2, pe2);
    o.x = o.x >= 0.0f ? o.x : 0.2f * o.x; o.y = o.y >= 0.0f ? o.y : 0.2f * o.y;
    o.z = o.z >= 0.0f ? o.z : 0.2f * o.z; o.w = o.w >= 0.0f ? o.w : 0.2f * o.w;
    *(float4*)&act2T[(64 + lane) * 4] = o;
  }
  __syncthreads();
  {
    float4 aA = make_float4(pb3a, pb3a, pb3a, pb3a);
    float4 aB = make_float4(pb3b, pb3b, pb3b, pb3b);
    for (int k = 0; k < 128; k++) {
      float wA = w3[k * 128 + lane];
      float wB = w3[k * 128 + 64 + lane];
      float4 a = *(const float4*)&act2T[k * 4];
      aA.x = fmaf(a.x, wA, aA.x); aA.y = fmaf(a.y, wA, aA.y);
      aA.z = fmaf(a.z, wA, aA.z); aA.w = fmaf(a.w, wA, aA.w);
      aB.x = fmaf(a.x, wB, aB.x); aB.y = fmaf(a.y, wB, aB.y);
      aB.z = fmaf(a.z, wB, aB.z); aB.w = fmaf(a.w, wB, aB.w);
    }
    float rA[4] = {aA.x, aA.y, aA.z, aA.w};
    float rB[4] = {aB.x, aB.y, aB.z, aB.w};
    #pragma unroll
    for (int r = 0; r < 4; r++) {
      float xA = fmaf(rA[r], pg3a, pe3a);
      float xB = fmaf(rB[r], pg3b, pe3b);
      xA = xA >= 0.0f ? xA : 0.2f * xA;
      xB = xB >= 0.0f ? xB : 0.2f * xB;
      out[(r0 + r) * 128 + lane] = xA;
      out[(r0 + r) * 128 + 64 + lane] = xB;
    }
  }
}

extern "C" void kernel_launch(void* const* d_in, const int* in_sizes, int n_in,
                              void* d_out, int out_size, void* d_ws, size_t ws_size,
                              hipStream_t stream) {
  const float* xyz  = (const float*)d_in[0];
  const float* feat = (const float*)d_in[1];
  const int*   smp  = (const int*)d_in[2];
  const float* w1   = (const float*)d_in[3];
  const float* b1   = (const float*)d_in[4];
  const float* g1   = (const float*)d_in[5];
  const float* be1  = (const float*)d_in[6];
  const float* w2   = (const float*)d_in[7];
  const float* b2   = (const float*)d_in[8];
  const float* g2   = (const float*)d_in[9];
  const float* be2  = (const float*)d_in[10];
  const float* w3   = (const float*)d_in[11];
  const float* b3   = (const float*)d_in[12];
  const float* g3   = (const float*)d_in[13];
  const float* be3  = (const float*)d_in[14];
  float* out = (float*)d_out;

  char* ws = (char*)d_ws;
  float4* P  = (float4*)(ws);                     // B*N*16   = 262144 B
  float*  TR = (float*)(ws + 262144);             // B*S*12*4 = 393216 B
  int*    AB = (int*)(ws + 655360);               // B*S*4*4  = 131072 B
  int*    AA = (int*)(ws + 786432);               // B*S*4*4  = 131072 B

  pack_kernel<<<96, 256, 0, stream>>>(xyz, smp, P, out);
  knn_kernel<<<1024, 256, 0, stream>>>(P, smp, TR, AB, AA);
  mlp_kernel<<<2048, 64, 0, stream>>>(TR, P, AB, AA, feat, smp,
                                      w1, b1, g1, be1, w2, b2, g2, be2,
                                      w3, b3, g3, be3, out + cB * cS * 3);
}